// Round 9
// baseline (517.872 us; speedup 1.0000x reference)
//
#include <hip/hip_runtime.h>

#define NNODES 50000
#define RREL 51
#define FIN 32
#define EDIM 32
#define CDIM 16
#define BB 30
#define NNZ_ 2000000
#define EPB 4096          // edges per block in hist/place
#define NBUK 391          // coarse dst buckets: dst>>7 (scan structure only)
#define PCAP_MAX 2800128  // NNZ + 50000*16 (min-pad worst case) + slack

typedef unsigned int uint32;
typedef unsigned short ushort;
typedef uint32 u32x2 __attribute__((ext_vector_type(2)));
typedef uint32 u32x4 __attribute__((ext_vector_type(4)));
typedef short bf16x8 __attribute__((ext_vector_type(8)));
typedef float f32x4 __attribute__((ext_vector_type(4)));
typedef float f32x16 __attribute__((ext_vector_type(16)));

// ---------- bf16 helpers (manual RNE) ----------
static __device__ __forceinline__ uint32 pack_bf16x2(float a, float b) {
    uint32 ua = __builtin_bit_cast(uint32, a);
    uint32 ub = __builtin_bit_cast(uint32, b);
    ua += 0x7fffu + ((ua >> 16) & 1u);
    ub += 0x7fffu + ((ub >> 16) & 1u);
    return (ua >> 16) | (ub & 0xffff0000u);
}
static __device__ __forceinline__ ushort bf16_1(float x) {
    uint32 u = __builtin_bit_cast(uint32, x);
    u += 0x7fffu + ((u >> 16) & 1u);
    return (ushort)(u >> 16);
}

// ---- weight build: bases only (comps folded per-edge in fused kernel) ----
// Wb layout (B-frag swizzled, k = b*32 + f, K = 960):
//   Wb[((k>>3)*FO + n)*8 + (k&7)] = bf16(bases[b][f][n])
__global__ void k_weights2(const float* __restrict__ bases1, const float* __restrict__ bases2,
                           ushort* __restrict__ Wb1, ushort* __restrict__ Wb2) {
    int i = blockIdx.x * 256 + threadIdx.x;
    if (i < 960 * 32) {                 // Wb1: K=960 (b*32+f), N=32 (e)
        int e = i & 31, k = i >> 5;
        int b = k >> 5, f = k & 31;
        float v = bases1[b * 1024 + f * 32 + e];
        Wb1[((k >> 3) * 32 + e) * 8 + (k & 7)] = bf16_1(v);
    }
    if (i < 960 * 16) {                 // Wb2: K=960 (b*32+h), N=16 (c)
        int e = i & 15, k = i >> 4;
        int b = k >> 5, h = k & 31;
        float v = bases2[b * 512 + h * 16 + e];
        Wb2[((k >> 3) * 16 + e) * 8 + (k & 7)] = bf16_1(v);
    }
}

// ---------------- fp32 features -> packed bf16 rows (64 B/row) ----------
__global__ void k_tobf16(const float2* __restrict__ src, uint32* __restrict__ dst, int n2) {
    int i = blockIdx.x * 256 + threadIdx.x;
    if (i < n2) {
        float2 f = src[i];
        dst[i] = pack_bf16x2(f.x, f.y);
    }
}

// ------------- per-dst degree histogram: streaming read, global atomics -------------
__global__ __launch_bounds__(1024) void k_dsthist(const int* __restrict__ rows,
                                                  int* __restrict__ dst_cnt) {
    size_t k = (size_t)blockIdx.x * EPB + (size_t)threadIdx.x * 4;
    if (k + 4 <= NNZ_) {
        int4 rw = *(const int4*)(rows + k);
        int rr[4] = {rw.x, rw.y, rw.z, rw.w};
#pragma unroll
        for (int j = 0; j < 4; j++) {
            int rel = rr[j] / NNODES;
            atomicAdd(&dst_cnt[rr[j] - rel * NNODES], 1);
        }
    } else {
        for (int j = 0; j < 4; j++)
            if (k + j < NNZ_) {
                int r = rows[k + j];
                int rel = r / NNODES;
                atomicAdd(&dst_cnt[r - rel * NNODES], 1);
            }
    }
}

// ---- per-bucket padded totals: sum over 128 dsts of max(16, ceil(cnt/16)*16) ----
__global__ __launch_bounds__(128) void k_pb(const int* __restrict__ dst_cnt,
                                            int* __restrict__ pbuk_cnt) {
    __shared__ int tot;
    int b = blockIdx.x, t = threadIdx.x;
    if (t == 0) tot = 0;
    __syncthreads();
    int d = (b << 7) + t;
    int v = 0;
    if (d < NNODES) {
        int c = dst_cnt[d];
        v = (c + 15) & ~15;
        if (v == 0) v = 16;               // empty dsts padded to 16 (non-empty invariant)
    }
    atomicAdd(&tot, v);
    __syncthreads();
    if (t == 0) pbuk_cnt[b] = tot;
}

// ---- wave-parallel exclusive scan over NBUK padded counts ----
__global__ void k_scan2(const int* __restrict__ pbuk_cnt, int* __restrict__ pbuk_base) {
    int t = threadIdx.x;                 // 64 threads
    int carry = 0;
    for (int c = 0; c < NBUK; c += 64) {
        int idx = c + t;
        int v = (idx < NBUK) ? pbuk_cnt[idx] : 0;
        int sum = v;
#pragma unroll
        for (int off = 1; off < 64; off <<= 1) {
            int u = __shfl_up(sum, off, 64);
            if (t >= off) sum += u;
        }
        if (idx < NBUK) pbuk_base[idx] = carry + sum - v;
        carry += __shfl(sum, 63, 64);
    }
    if (t == 0) pbuk_base[NBUK] = carry;
}

// ---- per-dst bases (block scan of 128 padded counts) + zero-fill pad tails ----
__global__ __launch_bounds__(128) void k_base(const int* __restrict__ dst_cnt,
                                              const int* __restrict__ pbuk_base,
                                              int* __restrict__ pdst_base,
                                              uint32* __restrict__ pe_sr,
                                              float* __restrict__ pe_val) {
    __shared__ int ssc[128];
    int b = blockIdx.x, t = threadIdx.x;
    int d = (b << 7) + t;
    int cnt = (d < NNODES) ? dst_cnt[d] : 0;
    int v = 0;
    if (d < NNODES) {
        v = (cnt + 15) & ~15;
        if (v == 0) v = 16;
    }
    ssc[t] = v;
    __syncthreads();
    for (int off = 1; off < 128; off <<= 1) {
        int u = (t >= off) ? ssc[t - off] : 0;
        __syncthreads();
        ssc[t] += u;
        __syncthreads();
    }
    int base = pbuk_base[b] + ssc[t] - v;
    if (d <= NNODES + 4) pdst_base[d] = base;
    for (int i = base + cnt; i < base + v; i++) { pe_sr[i] = 0u; pe_val[i] = 0.f; }
}

// ---- direct scatter: pos = pdst_base[dst] + atomic rank; streaming reads ----
__global__ __launch_bounds__(1024) void k_placeD(const int* __restrict__ rows,
                                                 const int* __restrict__ cols,
                                                 const float* __restrict__ vals,
                                                 const int* __restrict__ pdst_base,
                                                 int* __restrict__ dst_cur,
                                                 uint32* __restrict__ pe_sr,
                                                 float* __restrict__ pe_val) {
    size_t k = (size_t)blockIdx.x * EPB + (size_t)threadIdx.x * 4;
    if (k + 4 <= NNZ_) {
        int4 rw = *(const int4*)(rows + k);
        int4 cw = *(const int4*)(cols + k);
        float4 vw = *(const float4*)(vals + k);
        int rr[4] = {rw.x, rw.y, rw.z, rw.w};
        int cc[4] = {cw.x, cw.y, cw.z, cw.w};
        float vv[4] = {vw.x, vw.y, vw.z, vw.w};
#pragma unroll
        for (int j = 0; j < 4; j++) {
            int rel = rr[j] / NNODES;
            int dst = rr[j] - rel * NNODES;
            int pos = pdst_base[dst] + atomicAdd(&dst_cur[dst], 1);
            pe_sr[pos] = (uint32)cc[j] | ((uint32)rel << 16);
            pe_val[pos] = vv[j];
        }
    } else {
        for (int j = 0; j < 4; j++)
            if (k + j < NNZ_) {
                int r = rows[k + j];
                int rel = r / NNODES;
                int dst = r - rel * NNODES;
                int pos = pdst_base[dst] + atomicAdd(&dst_cur[dst], 1);
                pe_sr[pos] = (uint32)cols[k + j] | ((uint32)rel << 16);
                pe_val[pos] = vals[k + j];
            }
    }
}

// ======== fused layer (round-5 verbatim: measured 104 us — best of 5 schedule variants) ====
// per-dst u = sum_e (val*comps[rel,:]) (x) X[src]   (32x32x16 MFMA, K=edge windows of 16)
// then h[dst] = u_flat(960) @ bases_flat(960 x FO)  (16x16x32 MFMA, 4-dst batches)
// Pipeline: meta chunk c+1 prefetched (regs); X-rows for chunk c+1 gathered at end of
// chunk c via shfl'd srcs from the prefetched meta; cc-prep hoisted before the xst
// writes so the in-flight gathers land under it.
template <int FO, bool RELU, bool BF16OUT>
__global__ __launch_bounds__(256) void k_fused(const uint32* __restrict__ pe_sr,
                                               const float* __restrict__ pe_val,
                                               const int* __restrict__ pdst_base,
                                               const u32x4* __restrict__ Xb,
                                               const u32x4* __restrict__ Wb,
                                               const float* __restrict__ comps,
                                               const float* __restrict__ bias,
                                               void* __restrict__ outp) {
    __shared__ ushort comps_lb[RREL * 32];            // bf16 comps: 3.3 KB
    __shared__ uint32 eds[4][64];
    __shared__ float edv[4][64];
    __shared__ __align__(16) ushort xst[4][4][512];   // [wave][win][16 edges x 32 bf16]
    __shared__ __align__(16) ushort ubuf[4][4][968];  // [wave][slot][960 bf16]
    int t = threadIdx.x, lane = t & 63, wv = t >> 6;
    for (int i = t; i < RREL * 32; i += 256) {
        int r = i >> 5, b = i & 31;
        comps_lb[i] = (b < BB) ? bf16_1(comps[r * BB + b]) : (ushort)0;
    }
    __syncthreads();
    int m = lane & 31, hf = lane >> 5, k0 = hf * 8;
    int ln15 = lane & 15, quad = lane >> 4;
    int d0 = (blockIdx.x * 4 + wv) * 8;               // 8 dsts per wave; NNODES % 8 == 0
    if (d0 >= NNODES) return;                         // comps barrier already passed

    // A-operand prep for window wi (avq kept in named regs)
    auto ccprep = [&](int wi) -> u32x4 {
        float cc[8];
#pragma unroll
        for (int j = 0; j < 8; j++) {
            uint32 sr = eds[wv][wi * 16 + k0 + j];
            float vv = edv[wv][wi * 16 + k0 + j];
            uint32 cu = (uint32)comps_lb[((sr >> 16) << 5) | m] << 16;
            cc[j] = vv * __builtin_bit_cast(float, cu);
        }
        u32x4 r = { pack_bf16x2(cc[0], cc[1]), pack_bf16x2(cc[2], cc[3]),
                    pack_bf16x2(cc[4], cc[5]), pack_bf16x2(cc[6], cc[7]) };
        return r;
    };
    // B-operand read + MFMA for window wi
    auto dowin = [&](int wi, u32x4 avq, f32x16 a) -> f32x16 {
        const ushort* xs = &xst[wv][wi][0];
        uint32 b0 = (uint32)xs[(k0 + 0) * 32 + m] | ((uint32)xs[(k0 + 1) * 32 + m] << 16);
        uint32 b1 = (uint32)xs[(k0 + 2) * 32 + m] | ((uint32)xs[(k0 + 3) * 32 + m] << 16);
        uint32 b2 = (uint32)xs[(k0 + 4) * 32 + m] | ((uint32)xs[(k0 + 5) * 32 + m] << 16);
        uint32 b3 = (uint32)xs[(k0 + 6) * 32 + m] | ((uint32)xs[(k0 + 7) * 32 + m] << 16);
        u32x4 bvq = { b0, b1, b2, b3 };
        return __builtin_amdgcn_mfma_f32_32x32x16_bf16(
            __builtin_bit_cast(bf16x8, avq), __builtin_bit_cast(bf16x8, bvq), a, 0, 0, 0);
    };

    // ---- pipeline prologue: meta + X-gathers for the wave's first chunk ----
    int base0 = pdst_base[d0];
    uint32 pvs = __builtin_nontemporal_load(&pe_sr[base0 + lane]);
    float  pvv = __builtin_nontemporal_load(&pe_val[base0 + lane]);
    u32x4 gx0, gx1, gx2, gx3;
    {
        int s0_ = __shfl((int)pvs, (lane >> 2), 64);
        gx0 = Xb[(size_t)((uint32)s0_ & 0xFFFFu) * 4 + (lane & 3)];
        int s1_ = __shfl((int)pvs, 16 + (lane >> 2), 64);
        gx1 = Xb[(size_t)((uint32)s1_ & 0xFFFFu) * 4 + (lane & 3)];
        int s2_ = __shfl((int)pvs, 32 + (lane >> 2), 64);
        gx2 = Xb[(size_t)((uint32)s2_ & 0xFFFFu) * 4 + (lane & 3)];
        int s3_ = __shfl((int)pvs, 48 + (lane >> 2), 64);
        gx3 = Xb[(size_t)((uint32)s3_ & 0xFFFFu) * 4 + (lane & 3)];
    }

#pragma unroll 1
    for (int batch = 0; batch < 2; batch++) {
        int db = d0 + batch * 4;
        // ---- stage 1: accumulate u for 4 dsts into ubuf ----
#pragma unroll 1
        for (int s = 0; s < 4; s++) {
            int d = db + s;
            int lo = pdst_base[d], segEnd = pdst_base[d + 1];
            f32x16 acc;
#pragma unroll
            for (int i = 0; i < 16; i++) acc[i] = 0.f;
#pragma unroll 1
            for (int c0 = lo; c0 < segEnd; c0 += 64) {
                eds[wv][lane] = pvs;                  // stage current meta (reg -> LDS)
                edv[wv][lane] = pvv;
                // issue next meta (regions contiguous & 16-granular: next chunk at
                // min(c0+64, segEnd), even across dst boundaries)
                int nxt = c0 + 64; if (nxt > segEnd) nxt = segEnd;
                uint32 npvs = __builtin_nontemporal_load(&pe_sr[nxt + lane]);
                float  npvv = __builtin_nontemporal_load(&pe_val[nxt + lane]);
                int nwin = (segEnd - c0) >> 4;
                if (nwin > 4) nwin = 4;
                // cc-prep first: ~140 VALU ops cover the in-flight gx gathers
                u32x4 av0, av1, av2, av3;
                av0 = ccprep(0);
                if (nwin > 1) av1 = ccprep(1);
                if (nwin > 2) av2 = ccprep(2);
                if (nwin > 3) av3 = ccprep(3);
                // land the gathered X rows (issued one chunk ago) into LDS
                *(u32x4*)&xst[wv][0][lane * 8] = gx0;
                if (nwin > 1) *(u32x4*)&xst[wv][1][lane * 8] = gx1;
                if (nwin > 2) *(u32x4*)&xst[wv][2][lane * 8] = gx2;
                if (nwin > 3) *(u32x4*)&xst[wv][3][lane * 8] = gx3;
                // compute windows
                acc = dowin(0, av0, acc);
                if (nwin > 1) acc = dowin(1, av1, acc);
                if (nwin > 2) acc = dowin(2, av2, acc);
                if (nwin > 3) acc = dowin(3, av3, acc);
                // issue X-row gathers for the NEXT chunk from prefetched meta (regs)
                {
                    int s0_ = __shfl((int)npvs, (lane >> 2), 64);
                    gx0 = Xb[(size_t)((uint32)s0_ & 0xFFFFu) * 4 + (lane & 3)];
                    int s1_ = __shfl((int)npvs, 16 + (lane >> 2), 64);
                    gx1 = Xb[(size_t)((uint32)s1_ & 0xFFFFu) * 4 + (lane & 3)];
                    int s2_ = __shfl((int)npvs, 32 + (lane >> 2), 64);
                    gx2 = Xb[(size_t)((uint32)s2_ & 0xFFFFu) * 4 + (lane & 3)];
                    int s3_ = __shfl((int)npvs, 48 + (lane >> 2), 64);
                    gx3 = Xb[(size_t)((uint32)s3_ & 0xFFFFu) * 4 + (lane & 3)];
                }
                pvs = npvs; pvv = npvv;
            }
            // flush u (C-layout: col f = m, row b per reg) -> ubuf[wv][s] as bf16 rows k=b*32+f
#pragma unroll
            for (int r = 0; r < 16; r++) {
                int b = (r & 3) + 8 * (r >> 2) + 4 * hf;
                float vme = acc[r];
                float vot = __shfl_xor(vme, 1, 64);
                if (b < BB && !(m & 1)) {
                    *(uint32*)&ubuf[wv][s][b * 32 + m] = pack_bf16x2(vme, vot);
                }
            }
        }
        // ---- stage 2: h[db..db+3] = u @ bases_flat ----
        const int NT = FO / 16;
        f32x4 a2[NT];
#pragma unroll
        for (int tt = 0; tt < NT; tt++)
#pragma unroll
            for (int i = 0; i < 4; i++) a2[tt][i] = 0.f;
#pragma unroll 6
        for (int ks = 0; ks < 30; ks++) {
            bf16x8 af = *(const bf16x8*)&ubuf[wv][ln15 & 3][ks * 32 + quad * 8];
#pragma unroll
            for (int tt = 0; tt < NT; tt++) {
                bf16x8 bf2 = __builtin_bit_cast(bf16x8, Wb[(ks * 4 + quad) * FO + ln15 + 16 * tt]);
                a2[tt] = __builtin_amdgcn_mfma_f32_16x16x32_bf16(af, bf2, a2[tt], 0, 0, 0);
            }
        }
        if (quad == 0) {
#pragma unroll
            for (int r = 0; r < 4; r++) {
                int dst = db + r;
                if (dst < NNODES) {
                    if (BF16OUT) {
                        ushort* hp = (ushort*)outp;
#pragma unroll
                        for (int tt = 0; tt < NT; tt++) {
                            float o = a2[tt][r] + bias[ln15 + 16 * tt];
                            if (RELU) o = fmaxf(o, 0.f);
                            hp[(size_t)dst * FO + ln15 + 16 * tt] = bf16_1(o);
                        }
                    } else {
                        float o = a2[0][r] + bias[ln15];
                        if (RELU) o = fmaxf(o, 0.f);
                        ((float*)outp)[(size_t)dst * FO + ln15] = o;
                    }
                }
            }
        }
    }
}

extern "C" void kernel_launch(void* const* d_in, const int* in_sizes, int n_in,
                              void* d_out, int out_size, void* d_ws, size_t ws_size,
                              hipStream_t stream) {
    const float* features = (const float*)d_in[0];
    const float* vals     = (const float*)d_in[1];
    const float* comps1   = (const float*)d_in[2];
    const float* bases1   = (const float*)d_in[3];
    const float* bias1    = (const float*)d_in[4];
    const float* comps2   = (const float*)d_in[5];
    const float* bases2   = (const float*)d_in[6];
    const float* bias2    = (const float*)d_in[7];
    const int*   rows     = (const int*)d_in[8];
    const int*   cols     = (const int*)d_in[9];
    float* out = (float*)d_out;

    // ---- workspace layout (4-byte units); ~29 MB total ----
    float* ws = (float*)d_ws;
    size_t o = 0;
    ushort* Wb1 = (ushort*)(ws + o); o += 960 * 32 / 2;              // 15360 u32
    ushort* Wb2 = (ushort*)(ws + o); o += 960 * 16 / 2;              // 7680
    uint32* Xb  = (uint32*)(ws + o); o += (size_t)NNODES * 16;       // 3.2 MB (64 B bf16 rows)
    uint32* h1b = (uint32*)(ws + o); o += (size_t)NNODES * 16;       // 3.2 MB
    uint32* pe_sr  = (uint32*)(ws + o); o += PCAP_MAX;               // src|rel<<16, dst-sorted padded
    float*  pe_val = (float*)(ws + o);  o += PCAP_MAX;
    int* pdst_base = (int*)(ws + o); o += NNODES + 8;
    int* dst_cnt   = (int*)(ws + o); o += NNODES;                    // zeroed each launch
    int* dst_cur   = (int*)(ws + o); o += NNODES;                    // zeroed each launch
    int* pbuk_cnt  = (int*)(ws + o); o += NBUK;
    int* pbuk_base = (int*)(ws + o); o += NBUK + 1;

    const int NB = (NNZ_ + EPB - 1) / EPB;    // 489

    hipMemsetAsync(dst_cnt, 0, 2 * NNODES * sizeof(int), stream);    // dst_cnt + dst_cur

    k_weights2<<<(960 * 32 + 255) / 256, 256, 0, stream>>>(bases1, bases2, Wb1, Wb2);
    k_tobf16<<<(NNODES * FIN / 2 + 255) / 256, 256, 0, stream>>>((const float2*)features, Xb,
                                                                 NNODES * FIN / 2);
    k_dsthist<<<NB, 1024, 0, stream>>>(rows, dst_cnt);
    k_pb<<<NBUK, 128, 0, stream>>>(dst_cnt, pbuk_cnt);
    k_scan2<<<1, 64, 0, stream>>>(pbuk_cnt, pbuk_base);
    k_base<<<NBUK, 128, 0, stream>>>(dst_cnt, pbuk_base, pdst_base, pe_sr, pe_val);
    k_placeD<<<NB, 1024, 0, stream>>>(rows, cols, vals, pdst_base, dst_cur, pe_sr, pe_val);

    // 50000 dsts / 8 per wave / 4 waves per block = 1563 blocks (tail waves idle)
    k_fused<EDIM, true, true><<<(NNODES + 31) / 32, 256, 0, stream>>>(
        pe_sr, pe_val, pdst_base, (const u32x4*)Xb, (const u32x4*)Wb1, comps1, bias1, h1b);
    k_fused<CDIM, false, false><<<(NNODES + 31) / 32, 256, 0, stream>>>(
        pe_sr, pe_val, pdst_base, (const u32x4*)h1b, (const u32x4*)Wb2, comps2, bias2, out);
}

// Round 10
// 424.434 us; speedup vs baseline: 1.2201x; 1.2201x over previous
//
#include <hip/hip_runtime.h>

#define NNODES 50000
#define RREL 51
#define FIN 32
#define EDIM 32
#define CDIM 16
#define BB 30
#define NNZ_ 2000000
#define EPB 4096          // edges per block in hist/bucket
#define NBUK 391          // coarse dst buckets: dst>>7
#define PCAP_MAX 2800128  // NNZ + 50000*16 (min-pad worst case) + slack

typedef unsigned int uint32;
typedef unsigned short ushort;
typedef uint32 u32x2 __attribute__((ext_vector_type(2)));
typedef uint32 u32x4 __attribute__((ext_vector_type(4)));
typedef short bf16x8 __attribute__((ext_vector_type(8)));
typedef float f32x4 __attribute__((ext_vector_type(4)));
typedef float f32x16 __attribute__((ext_vector_type(16)));

// ---------- bf16 helpers (manual RNE) ----------
static __device__ __forceinline__ uint32 pack_bf16x2(float a, float b) {
    uint32 ua = __builtin_bit_cast(uint32, a);
    uint32 ub = __builtin_bit_cast(uint32, b);
    ua += 0x7fffu + ((ua >> 16) & 1u);
    ub += 0x7fffu + ((ub >> 16) & 1u);
    return (ua >> 16) | (ub & 0xffff0000u);
}
static __device__ __forceinline__ ushort bf16_1(float x) {
    uint32 u = __builtin_bit_cast(uint32, x);
    u += 0x7fffu + ((u >> 16) & 1u);
    return (ushort)(u >> 16);
}

// ---- weight build: bases only (comps folded per-edge in fused kernel) ----
// Wb layout (B-frag swizzled, k = b*32 + f, K = 960):
//   Wb[((k>>3)*FO + n)*8 + (k&7)] = bf16(bases[b][f][n])
__global__ void k_weights2(const float* __restrict__ bases1, const float* __restrict__ bases2,
                           ushort* __restrict__ Wb1, ushort* __restrict__ Wb2) {
    int i = blockIdx.x * 256 + threadIdx.x;
    if (i < 960 * 32) {                 // Wb1: K=960 (b*32+f), N=32 (e)
        int e = i & 31, k = i >> 5;
        int b = k >> 5, f = k & 31;
        float v = bases1[b * 1024 + f * 32 + e];
        Wb1[((k >> 3) * 32 + e) * 8 + (k & 7)] = bf16_1(v);
    }
    if (i < 960 * 16) {                 // Wb2: K=960 (b*32+h), N=16 (c)
        int e = i & 15, k = i >> 4;
        int b = k >> 5, h = k & 31;
        float v = bases2[b * 512 + h * 16 + e];
        Wb2[((k >> 3) * 16 + e) * 8 + (k & 7)] = bf16_1(v);
    }
}

// ---------------- fp32 features -> packed bf16 rows (64 B/row) ----------
__global__ void k_tobf16(const float2* __restrict__ src, uint32* __restrict__ dst, int n2) {
    int i = blockIdx.x * 256 + threadIdx.x;
    if (i < n2) {
        float2 f = src[i];
        dst[i] = pack_bf16x2(f.x, f.y);
    }
}

// ------------- combined histogram: bucket counts (LDS) + per-dst counts (global) ----------
__global__ __launch_bounds__(1024) void k_hist(const int* __restrict__ rows,
                                               int* __restrict__ buk_cnt,
                                               int* __restrict__ dst_cnt) {
    __shared__ int lc[NBUK];
    int t = threadIdx.x;
    if (t < NBUK) lc[t] = 0;
    __syncthreads();
    size_t k = (size_t)blockIdx.x * EPB + (size_t)t * 4;
    int rr[4];
    if (k + 4 <= NNZ_) {
        int4 rw = *(const int4*)(rows + k);
        rr[0] = rw.x; rr[1] = rw.y; rr[2] = rw.z; rr[3] = rw.w;
    } else {
#pragma unroll
        for (int j = 0; j < 4; j++) rr[j] = (k + j < NNZ_) ? rows[k + j] : -1;
    }
#pragma unroll
    for (int j = 0; j < 4; j++)
        if (rr[j] >= 0) {
            int rel = rr[j] / NNODES;
            int dst = rr[j] - rel * NNODES;
            atomicAdd(&lc[dst >> 7], 1);
            atomicAdd(&dst_cnt[dst], 1);
        }
    __syncthreads();
    if (t < NBUK) atomicAdd(&buk_cnt[t], lc[t]);
}

// ---- wave-parallel exclusive scan over NBUK bucket counts ----
__global__ void k_scan1(const int* __restrict__ buk_cnt, int* __restrict__ buk_base,
                        int* __restrict__ buk_cur) {
    int t = threadIdx.x;                 // 64 threads
    int carry = 0;
    for (int c = 0; c < NBUK; c += 64) {
        int idx = c + t;
        int v = (idx < NBUK) ? buk_cnt[idx] : 0;
        int sum = v;
#pragma unroll
        for (int off = 1; off < 64; off <<= 1) {
            int u = __shfl_up(sum, off, 64);
            if (t >= off) sum += u;
        }
        int exc = carry + sum - v;
        if (idx < NBUK) { buk_base[idx] = exc; buk_cur[idx] = exc; }
        carry += __shfl(sum, 63, 64);
    }
    if (t == 0) buk_base[NBUK] = carry;
}

// ------ LDS token counting sort into dst-buckets. tok = {dst|rel<<16, src|rel<<16} + val ----
__global__ __launch_bounds__(1024) void k_bucket2(const int* __restrict__ rows,
                                                  const int* __restrict__ cols,
                                                  const float* __restrict__ vals,
                                                  int* __restrict__ buk_cur,
                                                  u32x2* __restrict__ tok8,
                                                  float* __restrict__ sval_b) {
    __shared__ int bukc[NBUK], lb[NBUK], gb[NBUK];
    __shared__ int ssum[1024];
    __shared__ u32x2 st8[EPB];
    __shared__ float sv[EPB];
    int t = threadIdx.x;
    size_t base = (size_t)blockIdx.x * EPB;
    int total = (int)(((size_t)NNZ_ - base < (size_t)EPB) ? ((size_t)NNZ_ - base) : (size_t)EPB);
    if (t < NBUK) bukc[t] = 0;
    __syncthreads();
    size_t k = base + (size_t)t * 4;
    int bv[4]; uint32 tx[4], ty[4]; float vv[4];
    if (k + 4 <= NNZ_) {
        int4 rw = *(const int4*)(rows + k);
        int4 cw = *(const int4*)(cols + k);
        float4 vw = *(const float4*)(vals + k);
        int rr[4] = {rw.x, rw.y, rw.z, rw.w};
        int cc[4] = {cw.x, cw.y, cw.z, cw.w};
        vv[0] = vw.x; vv[1] = vw.y; vv[2] = vw.z; vv[3] = vw.w;
#pragma unroll
        for (int j = 0; j < 4; j++) {
            int rel = rr[j] / NNODES;
            int dst = rr[j] - rel * NNODES;
            bv[j] = dst >> 7;
            tx[j] = (uint32)dst | ((uint32)rel << 16);
            ty[j] = (uint32)cc[j] | ((uint32)rel << 16);
        }
    } else {
#pragma unroll
        for (int j = 0; j < 4; j++) {
            if (k + j < NNZ_) {
                int r = rows[k + j];
                int rel = r / NNODES;
                int dst = r - rel * NNODES;
                bv[j] = dst >> 7;
                tx[j] = (uint32)dst | ((uint32)rel << 16);
                ty[j] = (uint32)cols[k + j] | ((uint32)rel << 16);
                vv[j] = vals[k + j];
            } else bv[j] = -1;
        }
    }
#pragma unroll
    for (int j = 0; j < 4; j++)
        if (bv[j] >= 0) atomicAdd(&bukc[bv[j]], 1);
    __syncthreads();
    int v = (t < NBUK) ? bukc[t] : 0;
    ssum[t] = v;
    __syncthreads();
    for (int off = 1; off < 1024; off <<= 1) {
        int u = (t >= off) ? ssum[t - off] : 0;
        __syncthreads();
        ssum[t] += u;
        __syncthreads();
    }
    if (t < NBUK) { lb[t] = ssum[t] - v; gb[t] = atomicAdd(&buk_cur[t], v); }
    __syncthreads();
    if (t < NBUK) bukc[t] = 0;
    __syncthreads();
#pragma unroll
    for (int j = 0; j < 4; j++) {
        if (bv[j] >= 0) {
            int slot = lb[bv[j]] + atomicAdd(&bukc[bv[j]], 1);
            u32x2 w; w.x = tx[j]; w.y = ty[j];
            st8[slot] = w;
            sv[slot] = vv[j];
        }
    }
    __syncthreads();
    for (int s = t; s < total; s += 1024) {
        u32x2 w = st8[s];
        int bk = (int)((w.x & 0xFFFFu) >> 7);
        int pos = gb[bk] + (s - lb[bk]);
        tok8[pos] = w;
        sval_b[pos] = sv[s];
    }
}

// ---- per-bucket padded totals from dst_cnt: sum over 128 dsts of max(16, ceil16) ----
__global__ __launch_bounds__(128) void k_pb(const int* __restrict__ dst_cnt,
                                            int* __restrict__ pbuk_cnt) {
    __shared__ int tot;
    int b = blockIdx.x, t = threadIdx.x;
    if (t == 0) tot = 0;
    __syncthreads();
    int d = (b << 7) + t;
    int v = 0;
    if (d < NNODES) {
        int c = dst_cnt[d];
        v = (c + 15) & ~15;
        if (v == 0) v = 16;               // empty dsts padded to 16 (non-empty invariant)
    }
    atomicAdd(&tot, v);
    __syncthreads();
    if (t == 0) pbuk_cnt[b] = tot;
}

// ---- wave-parallel exclusive scan over NBUK padded counts ----
__global__ void k_scan2(const int* __restrict__ pbuk_cnt, int* __restrict__ pbuk_base) {
    int t = threadIdx.x;                 // 64 threads
    int carry = 0;
    for (int c = 0; c < NBUK; c += 64) {
        int idx = c + t;
        int v = (idx < NBUK) ? pbuk_cnt[idx] : 0;
        int sum = v;
#pragma unroll
        for (int off = 1; off < 64; off <<= 1) {
            int u = __shfl_up(sum, off, 64);
            if (t >= off) sum += u;
        }
        if (idx < NBUK) pbuk_base[idx] = carry + sum - v;
        carry += __shfl(sum, 63, 64);
    }
    if (t == 0) pbuk_base[NBUK] = carry;
}

// ---- per-dst bases (block scan of 128 padded counts) + zero-fill pad tails ----
__global__ __launch_bounds__(128) void k_base(const int* __restrict__ dst_cnt,
                                              const int* __restrict__ pbuk_base,
                                              int* __restrict__ pdst_base,
                                              uint32* __restrict__ pe_sr,
                                              float* __restrict__ pe_val) {
    __shared__ int ssc[128];
    int b = blockIdx.x, t = threadIdx.x;
    int d = (b << 7) + t;
    int cnt = (d < NNODES) ? dst_cnt[d] : 0;
    int v = 0;
    if (d < NNODES) {
        v = (cnt + 15) & ~15;
        if (v == 0) v = 16;
    }
    ssc[t] = v;
    __syncthreads();
    for (int off = 1; off < 128; off <<= 1) {
        int u = (t >= off) ? ssc[t - off] : 0;
        __syncthreads();
        ssc[t] += u;
        __syncthreads();
    }
    int base = pbuk_base[b] + ssc[t] - v;
    if (d <= NNODES + 4) pdst_base[d] = base;
    for (int i = base + cnt; i < base + v; i++) { pe_sr[i] = 0u; pe_val[i] = 0.f; }
}

// ---- scatter-only place: read bucket-grouped tok8, rank via LDS, write bucket-local pe ----
__global__ __launch_bounds__(256) void k_place2(const u32x2* __restrict__ tok8,
                                                const float* __restrict__ sval_b,
                                                const int* __restrict__ buk_base,
                                                const int* __restrict__ pdst_base,
                                                uint32* __restrict__ pe_sr,
                                                float* __restrict__ pe_val) {
    __shared__ int lrank[128];
    int b = blockIdx.x, t = threadIdx.x;
    if (t < 128) lrank[t] = 0;
    __syncthreads();
    int lo = buk_base[b], hi = buk_base[b + 1];
    int d0 = b << 7;
    for (int i = lo + t; i < hi; i += 256) {
        u32x2 w = tok8[i];
        float v = sval_b[i];
        int dl = (int)(w.x & 127u);
        int pos = pdst_base[d0 + dl] + atomicAdd(&lrank[dl], 1);
        pe_sr[pos] = w.y;
        pe_val[pos] = v;
    }
}

// ======== fused layer (round-5 verbatim: measured 104 us — best of 5 schedule variants) ====
// per-dst u = sum_e (val*comps[rel,:]) (x) X[src]   (32x32x16 MFMA, K=edge windows of 16)
// then h[dst] = u_flat(960) @ bases_flat(960 x FO)  (16x16x32 MFMA, 4-dst batches)
template <int FO, bool RELU, bool BF16OUT>
__global__ __launch_bounds__(256) void k_fused(const uint32* __restrict__ pe_sr,
                                               const float* __restrict__ pe_val,
                                               const int* __restrict__ pdst_base,
                                               const u32x4* __restrict__ Xb,
                                               const u32x4* __restrict__ Wb,
                                               const float* __restrict__ comps,
                                               const float* __restrict__ bias,
                                               void* __restrict__ outp) {
    __shared__ ushort comps_lb[RREL * 32];            // bf16 comps: 3.3 KB
    __shared__ uint32 eds[4][64];
    __shared__ float edv[4][64];
    __shared__ __align__(16) ushort xst[4][4][512];   // [wave][win][16 edges x 32 bf16]
    __shared__ __align__(16) ushort ubuf[4][4][968];  // [wave][slot][960 bf16]
    int t = threadIdx.x, lane = t & 63, wv = t >> 6;
    for (int i = t; i < RREL * 32; i += 256) {
        int r = i >> 5, b = i & 31;
        comps_lb[i] = (b < BB) ? bf16_1(comps[r * BB + b]) : (ushort)0;
    }
    __syncthreads();
    int m = lane & 31, hf = lane >> 5, k0 = hf * 8;
    int ln15 = lane & 15, quad = lane >> 4;
    int d0 = (blockIdx.x * 4 + wv) * 8;               // 8 dsts per wave; NNODES % 8 == 0
    if (d0 >= NNODES) return;                         // comps barrier already passed

    // A-operand prep for window wi (avq kept in named regs)
    auto ccprep = [&](int wi) -> u32x4 {
        float cc[8];
#pragma unroll
        for (int j = 0; j < 8; j++) {
            uint32 sr = eds[wv][wi * 16 + k0 + j];
            float vv = edv[wv][wi * 16 + k0 + j];
            uint32 cu = (uint32)comps_lb[((sr >> 16) << 5) | m] << 16;
            cc[j] = vv * __builtin_bit_cast(float, cu);
        }
        u32x4 r = { pack_bf16x2(cc[0], cc[1]), pack_bf16x2(cc[2], cc[3]),
                    pack_bf16x2(cc[4], cc[5]), pack_bf16x2(cc[6], cc[7]) };
        return r;
    };
    // B-operand read + MFMA for window wi
    auto dowin = [&](int wi, u32x4 avq, f32x16 a) -> f32x16 {
        const ushort* xs = &xst[wv][wi][0];
        uint32 b0 = (uint32)xs[(k0 + 0) * 32 + m] | ((uint32)xs[(k0 + 1) * 32 + m] << 16);
        uint32 b1 = (uint32)xs[(k0 + 2) * 32 + m] | ((uint32)xs[(k0 + 3) * 32 + m] << 16);
        uint32 b2 = (uint32)xs[(k0 + 4) * 32 + m] | ((uint32)xs[(k0 + 5) * 32 + m] << 16);
        uint32 b3 = (uint32)xs[(k0 + 6) * 32 + m] | ((uint32)xs[(k0 + 7) * 32 + m] << 16);
        u32x4 bvq = { b0, b1, b2, b3 };
        return __builtin_amdgcn_mfma_f32_32x32x16_bf16(
            __builtin_bit_cast(bf16x8, avq), __builtin_bit_cast(bf16x8, bvq), a, 0, 0, 0);
    };

    // ---- pipeline prologue: meta + X-gathers for the wave's first chunk ----
    int base0 = pdst_base[d0];
    uint32 pvs = __builtin_nontemporal_load(&pe_sr[base0 + lane]);
    float  pvv = __builtin_nontemporal_load(&pe_val[base0 + lane]);
    u32x4 gx0, gx1, gx2, gx3;
    {
        int s0_ = __shfl((int)pvs, (lane >> 2), 64);
        gx0 = Xb[(size_t)((uint32)s0_ & 0xFFFFu) * 4 + (lane & 3)];
        int s1_ = __shfl((int)pvs, 16 + (lane >> 2), 64);
        gx1 = Xb[(size_t)((uint32)s1_ & 0xFFFFu) * 4 + (lane & 3)];
        int s2_ = __shfl((int)pvs, 32 + (lane >> 2), 64);
        gx2 = Xb[(size_t)((uint32)s2_ & 0xFFFFu) * 4 + (lane & 3)];
        int s3_ = __shfl((int)pvs, 48 + (lane >> 2), 64);
        gx3 = Xb[(size_t)((uint32)s3_ & 0xFFFFu) * 4 + (lane & 3)];
    }

#pragma unroll 1
    for (int batch = 0; batch < 2; batch++) {
        int db = d0 + batch * 4;
        // ---- stage 1: accumulate u for 4 dsts into ubuf ----
#pragma unroll 1
        for (int s = 0; s < 4; s++) {
            int d = db + s;
            int lo = pdst_base[d], segEnd = pdst_base[d + 1];
            f32x16 acc;
#pragma unroll
            for (int i = 0; i < 16; i++) acc[i] = 0.f;
#pragma unroll 1
            for (int c0 = lo; c0 < segEnd; c0 += 64) {
                eds[wv][lane] = pvs;                  // stage current meta (reg -> LDS)
                edv[wv][lane] = pvv;
                // issue next meta (regions contiguous & 16-granular: next chunk at
                // min(c0+64, segEnd), even across dst boundaries)
                int nxt = c0 + 64; if (nxt > segEnd) nxt = segEnd;
                uint32 npvs = __builtin_nontemporal_load(&pe_sr[nxt + lane]);
                float  npvv = __builtin_nontemporal_load(&pe_val[nxt + lane]);
                int nwin = (segEnd - c0) >> 4;
                if (nwin > 4) nwin = 4;
                // cc-prep first: ~140 VALU ops cover the in-flight gx gathers
                u32x4 av0, av1, av2, av3;
                av0 = ccprep(0);
                if (nwin > 1) av1 = ccprep(1);
                if (nwin > 2) av2 = ccprep(2);
                if (nwin > 3) av3 = ccprep(3);
                // land the gathered X rows (issued one chunk ago) into LDS
                *(u32x4*)&xst[wv][0][lane * 8] = gx0;
                if (nwin > 1) *(u32x4*)&xst[wv][1][lane * 8] = gx1;
                if (nwin > 2) *(u32x4*)&xst[wv][2][lane * 8] = gx2;
                if (nwin > 3) *(u32x4*)&xst[wv][3][lane * 8] = gx3;
                // compute windows
                acc = dowin(0, av0, acc);
                if (nwin > 1) acc = dowin(1, av1, acc);
                if (nwin > 2) acc = dowin(2, av2, acc);
                if (nwin > 3) acc = dowin(3, av3, acc);
                // issue X-row gathers for the NEXT chunk from prefetched meta (regs)
                {
                    int s0_ = __shfl((int)npvs, (lane >> 2), 64);
                    gx0 = Xb[(size_t)((uint32)s0_ & 0xFFFFu) * 4 + (lane & 3)];
                    int s1_ = __shfl((int)npvs, 16 + (lane >> 2), 64);
                    gx1 = Xb[(size_t)((uint32)s1_ & 0xFFFFu) * 4 + (lane & 3)];
                    int s2_ = __shfl((int)npvs, 32 + (lane >> 2), 64);
                    gx2 = Xb[(size_t)((uint32)s2_ & 0xFFFFu) * 4 + (lane & 3)];
                    int s3_ = __shfl((int)npvs, 48 + (lane >> 2), 64);
                    gx3 = Xb[(size_t)((uint32)s3_ & 0xFFFFu) * 4 + (lane & 3)];
                }
                pvs = npvs; pvv = npvv;
            }
            // flush u (C-layout: col f = m, row b per reg) -> ubuf[wv][s] as bf16 rows k=b*32+f
#pragma unroll
            for (int r = 0; r < 16; r++) {
                int b = (r & 3) + 8 * (r >> 2) + 4 * hf;
                float vme = acc[r];
                float vot = __shfl_xor(vme, 1, 64);
                if (b < BB && !(m & 1)) {
                    *(uint32*)&ubuf[wv][s][b * 32 + m] = pack_bf16x2(vme, vot);
                }
            }
        }
        // ---- stage 2: h[db..db+3] = u @ bases_flat ----
        const int NT = FO / 16;
        f32x4 a2[NT];
#pragma unroll
        for (int tt = 0; tt < NT; tt++)
#pragma unroll
            for (int i = 0; i < 4; i++) a2[tt][i] = 0.f;
#pragma unroll 6
        for (int ks = 0; ks < 30; ks++) {
            bf16x8 af = *(const bf16x8*)&ubuf[wv][ln15 & 3][ks * 32 + quad * 8];
#pragma unroll
            for (int tt = 0; tt < NT; tt++) {
                bf16x8 bf2 = __builtin_bit_cast(bf16x8, Wb[(ks * 4 + quad) * FO + ln15 + 16 * tt]);
                a2[tt] = __builtin_amdgcn_mfma_f32_16x16x32_bf16(af, bf2, a2[tt], 0, 0, 0);
            }
        }
        if (quad == 0) {
#pragma unroll
            for (int r = 0; r < 4; r++) {
                int dst = db + r;
                if (dst < NNODES) {
                    if (BF16OUT) {
                        ushort* hp = (ushort*)outp;
#pragma unroll
                        for (int tt = 0; tt < NT; tt++) {
                            float o = a2[tt][r] + bias[ln15 + 16 * tt];
                            if (RELU) o = fmaxf(o, 0.f);
                            hp[(size_t)dst * FO + ln15 + 16 * tt] = bf16_1(o);
                        }
                    } else {
                        float o = a2[0][r] + bias[ln15];
                        if (RELU) o = fmaxf(o, 0.f);
                        ((float*)outp)[(size_t)dst * FO + ln15] = o;
                    }
                }
            }
        }
    }
}

extern "C" void kernel_launch(void* const* d_in, const int* in_sizes, int n_in,
                              void* d_out, int out_size, void* d_ws, size_t ws_size,
                              hipStream_t stream) {
    const float* features = (const float*)d_in[0];
    const float* vals     = (const float*)d_in[1];
    const float* comps1   = (const float*)d_in[2];
    const float* bases1   = (const float*)d_in[3];
    const float* bias1    = (const float*)d_in[4];
    const float* comps2   = (const float*)d_in[5];
    const float* bases2   = (const float*)d_in[6];
    const float* bias2    = (const float*)d_in[7];
    const int*   rows     = (const int*)d_in[8];
    const int*   cols     = (const int*)d_in[9];
    float* out = (float*)d_out;

    // ---- workspace layout (4-byte units); ~54 MB total ----
    float* ws = (float*)d_ws;
    size_t o = 0;
    ushort* Wb1 = (ushort*)(ws + o); o += 960 * 32 / 2;              // 15360 u32
    ushort* Wb2 = (ushort*)(ws + o); o += 960 * 16 / 2;              // 7680
    uint32* Xb  = (uint32*)(ws + o); o += (size_t)NNODES * 16;       // 3.2 MB (64 B bf16 rows)
    uint32* h1b = (uint32*)(ws + o); o += (size_t)NNODES * 16;       // 3.2 MB
    uint32* pe_sr  = (uint32*)(ws + o); o += PCAP_MAX;               // src|rel<<16, dst-sorted padded
    float*  pe_val = (float*)(ws + o);  o += PCAP_MAX;
    int* pdst_base = (int*)(ws + o); o += NNODES + 8;
    // contiguous zero region: dst_cnt .. buk_cnt
    int* dst_cnt   = (int*)(ws + o); o += NNODES;
    int* buk_cnt   = (int*)(ws + o); o += NBUK;
    int* buk_base  = (int*)(ws + o); o += NBUK + 1;
    int* buk_cur   = (int*)(ws + o); o += NBUK;
    int* pbuk_cnt  = (int*)(ws + o); o += NBUK;
    int* pbuk_base = (int*)(ws + o); o += NBUK + 1;
    o = (o + 1) & ~(size_t)1;
    u32x2* tok8 = (u32x2*)(ws + o); o += 2 * (size_t)NNZ_;           // 16 MB
    float* sval_b = (float*)(ws + o); o += (size_t)NNZ_;             // 8 MB

    const int NB = (NNZ_ + EPB - 1) / EPB;    // 489

    hipMemsetAsync(dst_cnt, 0, (NNODES + NBUK) * sizeof(int), stream);

    k_weights2<<<(960 * 32 + 255) / 256, 256, 0, stream>>>(bases1, bases2, Wb1, Wb2);
    k_tobf16<<<(NNODES * FIN / 2 + 255) / 256, 256, 0, stream>>>((const float2*)features, Xb,
                                                                 NNODES * FIN / 2);
    k_hist<<<NB, 1024, 0, stream>>>(rows, buk_cnt, dst_cnt);
    k_scan1<<<1, 64, 0, stream>>>(buk_cnt, buk_base, buk_cur);
    k_bucket2<<<NB, 1024, 0, stream>>>(rows, cols, vals, buk_cur, tok8, sval_b);
    k_pb<<<NBUK, 128, 0, stream>>>(dst_cnt, pbuk_cnt);
    k_scan2<<<1, 64, 0, stream>>>(pbuk_cnt, pbuk_base);
    k_base<<<NBUK, 128, 0, stream>>>(dst_cnt, pbuk_base, pdst_base, pe_sr, pe_val);
    k_place2<<<NBUK, 256, 0, stream>>>(tok8, sval_b, buk_base, pdst_base, pe_sr, pe_val);

    // 50000 dsts / 8 per wave / 4 waves per block = 1563 blocks (tail waves idle)
    k_fused<EDIM, true, true><<<(NNODES + 31) / 32, 256, 0, stream>>>(
        pe_sr, pe_val, pdst_base, (const u32x4*)Xb, (const u32x4*)Wb1, comps1, bias1, h1b);
    k_fused<CDIM, false, false><<<(NNODES + 31) / 32, 256, 0, stream>>>(
        pe_sr, pe_val, pdst_base, (const u32x4*)h1b, (const u32x4*)Wb2, comps2, bias2, out);
}

// Round 12
// 331.192 us; speedup vs baseline: 1.5637x; 1.2815x over previous
//
#include <hip/hip_runtime.h>

#define NNODES 50000
#define RREL 51
#define FIN 32
#define EDIM 32
#define CDIM 16
#define BB 30
#define NNZ_ 2000000
#define EPB 4096          // edges per block in hist/bucket
#define NBUK 391          // coarse dst buckets: dst>>7
#define PCAP_MAX 2800128  // NNZ + 50000*16 (min-pad worst case) + 128 slack

typedef unsigned int uint32;
typedef unsigned short ushort;
typedef uint32 u32x2 __attribute__((ext_vector_type(2)));
typedef uint32 u32x4 __attribute__((ext_vector_type(4)));
typedef short bf16x8 __attribute__((ext_vector_type(8)));
typedef float f32x4 __attribute__((ext_vector_type(4)));
typedef float f32x16 __attribute__((ext_vector_type(16)));

// ---------- bf16 helpers (manual RNE) ----------
static __device__ __forceinline__ uint32 pack_bf16x2(float a, float b) {
    uint32 ua = __builtin_bit_cast(uint32, a);
    uint32 ub = __builtin_bit_cast(uint32, b);
    ua += 0x7fffu + ((ua >> 16) & 1u);
    ub += 0x7fffu + ((ub >> 16) & 1u);
    return (ua >> 16) | (ub & 0xffff0000u);
}
static __device__ __forceinline__ ushort bf16_1(float x) {
    uint32 u = __builtin_bit_cast(uint32, x);
    u += 0x7fffu + ((u >> 16) & 1u);
    return (ushort)(u >> 16);
}

// ---- weight build: bases only (comps folded per-edge in fused kernel) ----
// Wb layout (B-frag swizzled, k = b*32 + f, K = 960):
//   Wb[((k>>3)*FO + n)*8 + (k&7)] = bf16(bases[b][f][n])
__global__ void k_weights2(const float* __restrict__ bases1, const float* __restrict__ bases2,
                           ushort* __restrict__ Wb1, ushort* __restrict__ Wb2) {
    int i = blockIdx.x * 256 + threadIdx.x;
    if (i < 960 * 32) {                 // Wb1: K=960 (b*32+f), N=32 (e)
        int e = i & 31, k = i >> 5;
        int b = k >> 5, f = k & 31;
        float v = bases1[b * 1024 + f * 32 + e];
        Wb1[((k >> 3) * 32 + e) * 8 + (k & 7)] = bf16_1(v);
    }
    if (i < 960 * 16) {                 // Wb2: K=960 (b*32+h), N=16 (c)
        int e = i & 15, k = i >> 4;
        int b = k >> 5, h = k & 31;
        float v = bases2[b * 512 + h * 16 + e];
        Wb2[((k >> 3) * 16 + e) * 8 + (k & 7)] = bf16_1(v);
    }
}

// ---------------- fp32 features -> packed bf16 rows (64 B/row) ----------
__global__ void k_tobf16(const float2* __restrict__ src, uint32* __restrict__ dst, int n2) {
    int i = blockIdx.x * 256 + threadIdx.x;
    if (i < n2) {
        float2 f = src[i];
        dst[i] = pack_bf16x2(f.x, f.y);
    }
}

// ------------- dst-bucket histogram: LDS atomics only, streaming read -------------
__global__ __launch_bounds__(1024) void k_bukhist(const int* __restrict__ rows,
                                                  int* __restrict__ buk_cnt) {
    __shared__ int lc[NBUK];
    int t = threadIdx.x;
    if (t < NBUK) lc[t] = 0;
    __syncthreads();
    size_t k = (size_t)blockIdx.x * EPB + (size_t)t * 4;
    int rr[4];
    if (k + 4 <= NNZ_) {
        int4 rw = *(const int4*)(rows + k);
        rr[0] = rw.x; rr[1] = rw.y; rr[2] = rw.z; rr[3] = rw.w;
    } else {
#pragma unroll
        for (int j = 0; j < 4; j++) rr[j] = (k + j < NNZ_) ? rows[k + j] : -1;
    }
#pragma unroll
    for (int j = 0; j < 4; j++)
        if (rr[j] >= 0) {
            int rel = rr[j] / NNODES;
            int dst = rr[j] - rel * NNODES;
            atomicAdd(&lc[dst >> 7], 1);
        }
    __syncthreads();
    if (t < NBUK) atomicAdd(&buk_cnt[t], lc[t]);
}

// ---- wave-parallel exclusive scan over NBUK bucket counts ----
__global__ void k_scan1(const int* __restrict__ buk_cnt, int* __restrict__ buk_base,
                        int* __restrict__ buk_cur) {
    int t = threadIdx.x;                 // 64 threads
    int carry = 0;
    for (int c = 0; c < NBUK; c += 64) {
        int idx = c + t;
        int v = (idx < NBUK) ? buk_cnt[idx] : 0;
        int sum = v;
#pragma unroll
        for (int off = 1; off < 64; off <<= 1) {
            int u = __shfl_up(sum, off, 64);
            if (t >= off) sum += u;
        }
        int exc = carry + sum - v;
        if (idx < NBUK) { buk_base[idx] = exc; buk_cur[idx] = exc; }
        carry += __shfl(sum, 63, 64);
    }
    if (t == 0) buk_base[NBUK] = carry;
}

// ------ LDS token counting sort into dst-buckets. tok = {dst|rel<<16, src|rel<<16} + val ----
__global__ __launch_bounds__(1024) void k_bucket2(const int* __restrict__ rows,
                                                  const int* __restrict__ cols,
                                                  const float* __restrict__ vals,
                                                  int* __restrict__ buk_cur,
                                                  u32x2* __restrict__ tok8,
                                                  float* __restrict__ sval_b) {
    __shared__ int bukc[NBUK], lb[NBUK], gb[NBUK];
    __shared__ int ssum[1024];
    __shared__ u32x2 st8[EPB];
    __shared__ float sv[EPB];
    int t = threadIdx.x;
    size_t base = (size_t)blockIdx.x * EPB;
    int total = (int)(((size_t)NNZ_ - base < (size_t)EPB) ? ((size_t)NNZ_ - base) : (size_t)EPB);
    if (t < NBUK) bukc[t] = 0;
    __syncthreads();
    size_t k = base + (size_t)t * 4;
    int bv[4]; uint32 tx[4], ty[4]; float vv[4];
    if (k + 4 <= NNZ_) {
        int4 rw = *(const int4*)(rows + k);
        int4 cw = *(const int4*)(cols + k);
        float4 vw = *(const float4*)(vals + k);
        int rr[4] = {rw.x, rw.y, rw.z, rw.w};
        int cc[4] = {cw.x, cw.y, cw.z, cw.w};
        vv[0] = vw.x; vv[1] = vw.y; vv[2] = vw.z; vv[3] = vw.w;
#pragma unroll
        for (int j = 0; j < 4; j++) {
            int rel = rr[j] / NNODES;
            int dst = rr[j] - rel * NNODES;
            bv[j] = dst >> 7;
            tx[j] = (uint32)dst | ((uint32)rel << 16);
            ty[j] = (uint32)cc[j] | ((uint32)rel << 16);
        }
    } else {
#pragma unroll
        for (int j = 0; j < 4; j++) {
            if (k + j < NNZ_) {
                int r = rows[k + j];
                int rel = r / NNODES;
                int dst = r - rel * NNODES;
                bv[j] = dst >> 7;
                tx[j] = (uint32)dst | ((uint32)rel << 16);
                ty[j] = (uint32)cols[k + j] | ((uint32)rel << 16);
                vv[j] = vals[k + j];
            } else bv[j] = -1;
        }
    }
#pragma unroll
    for (int j = 0; j < 4; j++)
        if (bv[j] >= 0) atomicAdd(&bukc[bv[j]], 1);
    __syncthreads();
    int v = (t < NBUK) ? bukc[t] : 0;
    ssum[t] = v;
    __syncthreads();
    for (int off = 1; off < 1024; off <<= 1) {
        int u = (t >= off) ? ssum[t - off] : 0;
        __syncthreads();
        ssum[t] += u;
        __syncthreads();
    }
    if (t < NBUK) { lb[t] = ssum[t] - v; gb[t] = atomicAdd(&buk_cur[t], v); }
    __syncthreads();
    if (t < NBUK) bukc[t] = 0;
    __syncthreads();
#pragma unroll
    for (int j = 0; j < 4; j++) {
        if (bv[j] >= 0) {
            int slot = lb[bv[j]] + atomicAdd(&bukc[bv[j]], 1);
            u32x2 w; w.x = tx[j]; w.y = ty[j];
            st8[slot] = w;
            sv[slot] = vv[j];
        }
    }
    __syncthreads();
    for (int s = t; s < total; s += 1024) {
        u32x2 w = st8[s];
        int bk = (int)((w.x & 0xFFFFu) >> 7);
        int pos = gb[bk] + (s - lb[bk]);
        tok8[pos] = w;
        sval_b[pos] = sv[s];
    }
}

// ---- fused count + rank + scatter per bucket. Region base via ONE global atomicAdd.
// ---- Unordered allocation is safe because segment ENDS are now stored explicitly
// ---- (pdst_end[d] = bbase + inclusive_scan) — the r11 bug was reading pdst_base[d+1]
// ---- across a bucket boundary, where the neighbor's unordered base is unrelated.
__global__ __launch_bounds__(256) void k_place3(const u32x2* __restrict__ tok8,
                                                const float* __restrict__ sval_b,
                                                const int* __restrict__ buk_base,
                                                int* __restrict__ alloc_cur,
                                                int* __restrict__ pdst_base,
                                                int* __restrict__ pdst_end,
                                                uint32* __restrict__ pe_sr,
                                                float* __restrict__ pe_val) {
    __shared__ int lcnt[128], lexc[128], lrank[128], ssc[128];
    __shared__ int bbase;
    int b = blockIdx.x, t = threadIdx.x;
    int lo = buk_base[b], hi = buk_base[b + 1];
    if (t < 128) { lcnt[t] = 0; lrank[t] = 0; }
    __syncthreads();
    for (int i = lo + t; i < hi; i += 256) atomicAdd(&lcnt[tok8[i].x & 127], 1);
    __syncthreads();
    int v = 0;
    int d = (b << 7) + t;
    if (t < 128) {
        v = (lcnt[t] + 15) & ~15;
        if (d < NNODES && v == 0) v = 16;
        if (d >= NNODES) v = 0;
        ssc[t] = v;
    }
    __syncthreads();
    for (int off = 1; off < 128; off <<= 1) {
        int u = (t >= off && t < 128) ? ssc[t - off] : 0;
        __syncthreads();
        if (t < 128) ssc[t] += u;
        __syncthreads();
    }
    if (t == 0) bbase = atomicAdd(alloc_cur, ssc[127]);
    __syncthreads();
    if (t < 128) {
        lexc[t] = ssc[t] - v;
        if (d < NNODES) {
            pdst_base[d] = bbase + lexc[t];
            pdst_end[d]  = bbase + ssc[t];   // within-bucket: == pdst_base[d+1]
        }
    }
    __syncthreads();
    for (int i = lo + t; i < hi; i += 256) {
        u32x2 w = tok8[i];
        float sv = sval_b[i];
        int dl = (int)(w.x & 127u);
        int pos = bbase + lexc[dl] + atomicAdd(&lrank[dl], 1);
        pe_sr[pos] = w.y;
        pe_val[pos] = sv;
    }
    if (t < 128 && d < NNODES) {
        int s0 = bbase + lexc[t] + lcnt[t];
        int s1 = bbase + lexc[t] + v;
        for (int i = s0; i < s1; i++) { pe_sr[i] = 0u; pe_val[i] = 0.f; }
    }
}

// ======== fused layer (round-5 schedule, measured 104 us; sole change: segEnd comes
// ======== from pdst_end[d] instead of pdst_base[d+1] to support unordered buckets) ====
// per-dst u = sum_e (val*comps[rel,:]) (x) X[src]   (32x32x16 MFMA, K=edge windows of 16)
// then h[dst] = u_flat(960) @ bases_flat(960 x FO)  (16x16x32 MFMA, 4-dst batches)
template <int FO, bool RELU, bool BF16OUT>
__global__ __launch_bounds__(256) void k_fused(const uint32* __restrict__ pe_sr,
                                               const float* __restrict__ pe_val,
                                               const int* __restrict__ pdst_base,
                                               const int* __restrict__ pdst_end,
                                               const u32x4* __restrict__ Xb,
                                               const u32x4* __restrict__ Wb,
                                               const float* __restrict__ comps,
                                               const float* __restrict__ bias,
                                               void* __restrict__ outp) {
    __shared__ ushort comps_lb[RREL * 32];            // bf16 comps: 3.3 KB
    __shared__ uint32 eds[4][64];
    __shared__ float edv[4][64];
    __shared__ __align__(16) ushort xst[4][4][512];   // [wave][win][16 edges x 32 bf16]
    __shared__ __align__(16) ushort ubuf[4][4][968];  // [wave][slot][960 bf16]
    int t = threadIdx.x, lane = t & 63, wv = t >> 6;
    for (int i = t; i < RREL * 32; i += 256) {
        int r = i >> 5, b = i & 31;
        comps_lb[i] = (b < BB) ? bf16_1(comps[r * BB + b]) : (ushort)0;
    }
    __syncthreads();
    int m = lane & 31, hf = lane >> 5, k0 = hf * 8;
    int ln15 = lane & 15, quad = lane >> 4;
    int d0 = (blockIdx.x * 4 + wv) * 8;               // 8 dsts per wave; NNODES % 8 == 0
    if (d0 >= NNODES) return;                         // comps barrier already passed

    // A-operand prep for window wi (avq kept in named regs)
    auto ccprep = [&](int wi) -> u32x4 {
        float cc[8];
#pragma unroll
        for (int j = 0; j < 8; j++) {
            uint32 sr = eds[wv][wi * 16 + k0 + j];
            float vv = edv[wv][wi * 16 + k0 + j];
            uint32 cu = (uint32)comps_lb[((sr >> 16) << 5) | m] << 16;
            cc[j] = vv * __builtin_bit_cast(float, cu);
        }
        u32x4 r = { pack_bf16x2(cc[0], cc[1]), pack_bf16x2(cc[2], cc[3]),
                    pack_bf16x2(cc[4], cc[5]), pack_bf16x2(cc[6], cc[7]) };
        return r;
    };
    // B-operand read + MFMA for window wi
    auto dowin = [&](int wi, u32x4 avq, f32x16 a) -> f32x16 {
        const ushort* xs = &xst[wv][wi][0];
        uint32 b0 = (uint32)xs[(k0 + 0) * 32 + m] | ((uint32)xs[(k0 + 1) * 32 + m] << 16);
        uint32 b1 = (uint32)xs[(k0 + 2) * 32 + m] | ((uint32)xs[(k0 + 3) * 32 + m] << 16);
        uint32 b2 = (uint32)xs[(k0 + 4) * 32 + m] | ((uint32)xs[(k0 + 5) * 32 + m] << 16);
        uint32 b3 = (uint32)xs[(k0 + 6) * 32 + m] | ((uint32)xs[(k0 + 7) * 32 + m] << 16);
        u32x4 bvq = { b0, b1, b2, b3 };
        return __builtin_amdgcn_mfma_f32_32x32x16_bf16(
            __builtin_bit_cast(bf16x8, avq), __builtin_bit_cast(bf16x8, bvq), a, 0, 0, 0);
    };

    // ---- pipeline prologue: meta + X-gathers for the wave's first chunk ----
    int base0 = pdst_base[d0];
    uint32 pvs = __builtin_nontemporal_load(&pe_sr[base0 + lane]);
    float  pvv = __builtin_nontemporal_load(&pe_val[base0 + lane]);
    u32x4 gx0, gx1, gx2, gx3;
    {
        int s0_ = __shfl((int)pvs, (lane >> 2), 64);
        gx0 = Xb[(size_t)((uint32)s0_ & 0xFFFFu) * 4 + (lane & 3)];
        int s1_ = __shfl((int)pvs, 16 + (lane >> 2), 64);
        gx1 = Xb[(size_t)((uint32)s1_ & 0xFFFFu) * 4 + (lane & 3)];
        int s2_ = __shfl((int)pvs, 32 + (lane >> 2), 64);
        gx2 = Xb[(size_t)((uint32)s2_ & 0xFFFFu) * 4 + (lane & 3)];
        int s3_ = __shfl((int)pvs, 48 + (lane >> 2), 64);
        gx3 = Xb[(size_t)((uint32)s3_ & 0xFFFFu) * 4 + (lane & 3)];
    }

#pragma unroll 1
    for (int batch = 0; batch < 2; batch++) {
        int db = d0 + batch * 4;
        // ---- stage 1: accumulate u for 4 dsts into ubuf ----
#pragma unroll 1
        for (int s = 0; s < 4; s++) {
            int d = db + s;
            int lo = pdst_base[d], segEnd = pdst_end[d];
            f32x16 acc;
#pragma unroll
            for (int i = 0; i < 16; i++) acc[i] = 0.f;
#pragma unroll 1
            for (int c0 = lo; c0 < segEnd; c0 += 64) {
                eds[wv][lane] = pvs;                  // stage current meta (reg -> LDS)
                edv[wv][lane] = pvv;
                // issue next meta (regions contiguous & 16-granular within the wave's
                // 8-dst group: next chunk at min(c0+64, segEnd), even across dsts)
                int nxt = c0 + 64; if (nxt > segEnd) nxt = segEnd;
                uint32 npvs = __builtin_nontemporal_load(&pe_sr[nxt + lane]);
                float  npvv = __builtin_nontemporal_load(&pe_val[nxt + lane]);
                int nwin = (segEnd - c0) >> 4;
                if (nwin > 4) nwin = 4;
                // cc-prep first: ~140 VALU ops cover the in-flight gx gathers
                u32x4 av0, av1, av2, av3;
                av0 = ccprep(0);
                if (nwin > 1) av1 = ccprep(1);
                if (nwin > 2) av2 = ccprep(2);
                if (nwin > 3) av3 = ccprep(3);
                // land the gathered X rows (issued one chunk ago) into LDS
                *(u32x4*)&xst[wv][0][lane * 8] = gx0;
                if (nwin > 1) *(u32x4*)&xst[wv][1][lane * 8] = gx1;
                if (nwin > 2) *(u32x4*)&xst[wv][2][lane * 8] = gx2;
                if (nwin > 3) *(u32x4*)&xst[wv][3][lane * 8] = gx3;
                // compute windows
                acc = dowin(0, av0, acc);
                if (nwin > 1) acc = dowin(1, av1, acc);
                if (nwin > 2) acc = dowin(2, av2, acc);
                if (nwin > 3) acc = dowin(3, av3, acc);
                // issue X-row gathers for the NEXT chunk from prefetched meta (regs)
                {
                    int s0_ = __shfl((int)npvs, (lane >> 2), 64);
                    gx0 = Xb[(size_t)((uint32)s0_ & 0xFFFFu) * 4 + (lane & 3)];
                    int s1_ = __shfl((int)npvs, 16 + (lane >> 2), 64);
                    gx1 = Xb[(size_t)((uint32)s1_ & 0xFFFFu) * 4 + (lane & 3)];
                    int s2_ = __shfl((int)npvs, 32 + (lane >> 2), 64);
                    gx2 = Xb[(size_t)((uint32)s2_ & 0xFFFFu) * 4 + (lane & 3)];
                    int s3_ = __shfl((int)npvs, 48 + (lane >> 2), 64);
                    gx3 = Xb[(size_t)((uint32)s3_ & 0xFFFFu) * 4 + (lane & 3)];
                }
                pvs = npvs; pvv = npvv;
            }
            // flush u (C-layout: col f = m, row b per reg) -> ubuf[wv][s] as bf16 rows k=b*32+f
#pragma unroll
            for (int r = 0; r < 16; r++) {
                int b = (r & 3) + 8 * (r >> 2) + 4 * hf;
                float vme = acc[r];
                float vot = __shfl_xor(vme, 1, 64);
                if (b < BB && !(m & 1)) {
                    *(uint32*)&ubuf[wv][s][b * 32 + m] = pack_bf16x2(vme, vot);
                }
            }
        }
        // ---- stage 2: h[db..db+3] = u @ bases_flat ----
        const int NT = FO / 16;
        f32x4 a2[NT];
#pragma unroll
        for (int tt = 0; tt < NT; tt++)
#pragma unroll
            for (int i = 0; i < 4; i++) a2[tt][i] = 0.f;
#pragma unroll 6
        for (int ks = 0; ks < 30; ks++) {
            bf16x8 af = *(const bf16x8*)&ubuf[wv][ln15 & 3][ks * 32 + quad * 8];
#pragma unroll
            for (int tt = 0; tt < NT; tt++) {
                bf16x8 bf2 = __builtin_bit_cast(bf16x8, Wb[(ks * 4 + quad) * FO + ln15 + 16 * tt]);
                a2[tt] = __builtin_amdgcn_mfma_f32_16x16x32_bf16(af, bf2, a2[tt], 0, 0, 0);
            }
        }
        if (quad == 0) {
#pragma unroll
            for (int r = 0; r < 4; r++) {
                int dst = db + r;
                if (dst < NNODES) {
                    if (BF16OUT) {
                        ushort* hp = (ushort*)outp;
#pragma unroll
                        for (int tt = 0; tt < NT; tt++) {
                            float o = a2[tt][r] + bias[ln15 + 16 * tt];
                            if (RELU) o = fmaxf(o, 0.f);
                            hp[(size_t)dst * FO + ln15 + 16 * tt] = bf16_1(o);
                        }
                    } else {
                        float o = a2[0][r] + bias[ln15];
                        if (RELU) o = fmaxf(o, 0.f);
                        ((float*)outp)[(size_t)dst * FO + ln15] = o;
                    }
                }
            }
        }
    }
}

extern "C" void kernel_launch(void* const* d_in, const int* in_sizes, int n_in,
                              void* d_out, int out_size, void* d_ws, size_t ws_size,
                              hipStream_t stream) {
    const float* features = (const float*)d_in[0];
    const float* vals     = (const float*)d_in[1];
    const float* comps1   = (const float*)d_in[2];
    const float* bases1   = (const float*)d_in[3];
    const float* bias1    = (const float*)d_in[4];
    const float* comps2   = (const float*)d_in[5];
    const float* bases2   = (const float*)d_in[6];
    const float* bias2    = (const float*)d_in[7];
    const int*   rows     = (const int*)d_in[8];
    const int*   cols     = (const int*)d_in[9];
    float* out = (float*)d_out;

    // ---- workspace layout (4-byte units); ~54 MB total ----
    float* ws = (float*)d_ws;
    size_t o = 0;
    ushort* Wb1 = (ushort*)(ws + o); o += 960 * 32 / 2;              // 15360 u32
    ushort* Wb2 = (ushort*)(ws + o); o += 960 * 16 / 2;              // 7680
    uint32* Xb  = (uint32*)(ws + o); o += (size_t)NNODES * 16;       // 3.2 MB (64 B bf16 rows)
    uint32* h1b = (uint32*)(ws + o); o += (size_t)NNODES * 16;       // 3.2 MB
    uint32* pe_sr  = (uint32*)(ws + o); o += PCAP_MAX;               // src|rel<<16, dst-sorted padded
    float*  pe_val = (float*)(ws + o);  o += PCAP_MAX;
    int* pdst_base = (int*)(ws + o); o += NNODES + 8;
    int* pdst_end  = (int*)(ws + o); o += NNODES + 8;
    // contiguous zero region: buk_cnt .. alloc_cur
    int* buk_cnt   = (int*)(ws + o); o += NBUK;
    int* alloc_cur = (int*)(ws + o); o += 1;
    int* buk_base  = (int*)(ws + o); o += NBUK + 1;
    int* buk_cur   = (int*)(ws + o); o += NBUK;
    o = (o + 1) & ~(size_t)1;
    u32x2* tok8 = (u32x2*)(ws + o); o += 2 * (size_t)NNZ_;           // 16 MB
    float* sval_b = (float*)(ws + o); o += (size_t)NNZ_;             // 8 MB

    const int NB = (NNZ_ + EPB - 1) / EPB;    // 489

    hipMemsetAsync(buk_cnt, 0, (NBUK + 1) * sizeof(int), stream);    // buk_cnt + alloc_cur

    k_weights2<<<(960 * 32 + 255) / 256, 256, 0, stream>>>(bases1, bases2, Wb1, Wb2);
    k_tobf16<<<(NNODES * FIN / 2 + 255) / 256, 256, 0, stream>>>((const float2*)features, Xb,
                                                                 NNODES * FIN / 2);
    k_bukhist<<<NB, 1024, 0, stream>>>(rows, buk_cnt);
    k_scan1<<<1, 64, 0, stream>>>(buk_cnt, buk_base, buk_cur);
    k_bucket2<<<NB, 1024, 0, stream>>>(rows, cols, vals, buk_cur, tok8, sval_b);
    k_place3<<<NBUK, 256, 0, stream>>>(tok8, sval_b, buk_base, alloc_cur, pdst_base, pdst_end,
                                       pe_sr, pe_val);

    // 50000 dsts / 8 per wave / 4 waves per block = 1563 blocks (tail waves idle)
    k_fused<EDIM, true, true><<<(NNODES + 31) / 32, 256, 0, stream>>>(
        pe_sr, pe_val, pdst_base, pdst_end, (const u32x4*)Xb, (const u32x4*)Wb1, comps1, bias1, h1b);
    k_fused<CDIM, false, false><<<(NNODES + 31) / 32, 256, 0, stream>>>(
        pe_sr, pe_val, pdst_base, pdst_end, (const u32x4*)h1b, (const u32x4*)Wb2, comps2, bias2, out);
}

// Round 13
// 316.494 us; speedup vs baseline: 1.6363x; 1.0464x over previous
//
#include <hip/hip_runtime.h>

#define NNODES 50000
#define RREL 51
#define FIN 32
#define EDIM 32
#define CDIM 16
#define BB 30
#define NNZ_ 2000000
#define EPB 4096          // edges per block in hist/bucket
#define NBUK 391          // coarse dst buckets: dst>>7
#define PCAP_MAX 2800128  // NNZ + 50000*16 (min-pad worst case) + 128 slack

typedef unsigned int uint32;
typedef unsigned short ushort;
typedef uint32 u32x2 __attribute__((ext_vector_type(2)));
typedef uint32 u32x4 __attribute__((ext_vector_type(4)));
typedef short bf16x8 __attribute__((ext_vector_type(8)));
typedef float f32x4 __attribute__((ext_vector_type(4)));
typedef float f32x16 __attribute__((ext_vector_type(16)));

// ---------- bf16 helpers (manual RNE) ----------
static __device__ __forceinline__ uint32 pack_bf16x2(float a, float b) {
    uint32 ua = __builtin_bit_cast(uint32, a);
    uint32 ub = __builtin_bit_cast(uint32, b);
    ua += 0x7fffu + ((ua >> 16) & 1u);
    ub += 0x7fffu + ((ub >> 16) & 1u);
    return (ua >> 16) | (ub & 0xffff0000u);
}
static __device__ __forceinline__ ushort bf16_1(float x) {
    uint32 u = __builtin_bit_cast(uint32, x);
    u += 0x7fffu + ((u >> 16) & 1u);
    return (ushort)(u >> 16);
}

// ---- weight build: bases only (comps folded per-edge in fused kernel) ----
// Wb layout (B-frag swizzled, k = b*32 + f, K = 960):
//   Wb[((k>>3)*FO + n)*8 + (k&7)] = bf16(bases[b][f][n])
__global__ void k_weights2(const float* __restrict__ bases1, const float* __restrict__ bases2,
                           ushort* __restrict__ Wb1, ushort* __restrict__ Wb2) {
    int i = blockIdx.x * 256 + threadIdx.x;
    if (i < 960 * 32) {                 // Wb1: K=960 (b*32+f), N=32 (e)
        int e = i & 31, k = i >> 5;
        int b = k >> 5, f = k & 31;
        float v = bases1[b * 1024 + f * 32 + e];
        Wb1[((k >> 3) * 32 + e) * 8 + (k & 7)] = bf16_1(v);
    }
    if (i < 960 * 16) {                 // Wb2: K=960 (b*32+h), N=16 (c)
        int e = i & 15, k = i >> 4;
        int b = k >> 5, h = k & 31;
        float v = bases2[b * 512 + h * 16 + e];
        Wb2[((k >> 3) * 16 + e) * 8 + (k & 7)] = bf16_1(v);
    }
}

// ---------------- fp32 features -> packed bf16 rows (64 B/row) ----------
__global__ void k_tobf16(const float2* __restrict__ src, uint32* __restrict__ dst, int n2) {
    int i = blockIdx.x * 256 + threadIdx.x;
    if (i < n2) {
        float2 f = src[i];
        dst[i] = pack_bf16x2(f.x, f.y);
    }
}

// ------------- dst-bucket histogram: LDS atomics only, streaming read -------------
__global__ __launch_bounds__(1024) void k_bukhist(const int* __restrict__ rows,
                                                  int* __restrict__ buk_cnt) {
    __shared__ int lc[NBUK];
    int t = threadIdx.x;
    if (t < NBUK) lc[t] = 0;
    __syncthreads();
    size_t k = (size_t)blockIdx.x * EPB + (size_t)t * 4;
    int rr[4];
    if (k + 4 <= NNZ_) {
        int4 rw = *(const int4*)(rows + k);
        rr[0] = rw.x; rr[1] = rw.y; rr[2] = rw.z; rr[3] = rw.w;
    } else {
#pragma unroll
        for (int j = 0; j < 4; j++) rr[j] = (k + j < NNZ_) ? rows[k + j] : -1;
    }
#pragma unroll
    for (int j = 0; j < 4; j++)
        if (rr[j] >= 0) {
            int rel = rr[j] / NNODES;
            int dst = rr[j] - rel * NNODES;
            atomicAdd(&lc[dst >> 7], 1);
        }
    __syncthreads();
    if (t < NBUK) atomicAdd(&buk_cnt[t], lc[t]);
}

// ---- wave-parallel exclusive scan over NBUK bucket counts ----
__global__ void k_scan1(const int* __restrict__ buk_cnt, int* __restrict__ buk_base,
                        int* __restrict__ buk_cur) {
    int t = threadIdx.x;                 // 64 threads
    int carry = 0;
    for (int c = 0; c < NBUK; c += 64) {
        int idx = c + t;
        int v = (idx < NBUK) ? buk_cnt[idx] : 0;
        int sum = v;
#pragma unroll
        for (int off = 1; off < 64; off <<= 1) {
            int u = __shfl_up(sum, off, 64);
            if (t >= off) sum += u;
        }
        int exc = carry + sum - v;
        if (idx < NBUK) { buk_base[idx] = exc; buk_cur[idx] = exc; }
        carry += __shfl(sum, 63, 64);
    }
    if (t == 0) buk_base[NBUK] = carry;
}

// ------ LDS token counting sort into dst-buckets. tok = {dst|rel<<16, src|rel<<16} + val ----
__global__ __launch_bounds__(1024) void k_bucket2(const int* __restrict__ rows,
                                                  const int* __restrict__ cols,
                                                  const float* __restrict__ vals,
                                                  int* __restrict__ buk_cur,
                                                  u32x2* __restrict__ tok8,
                                                  float* __restrict__ sval_b) {
    __shared__ int bukc[NBUK], lb[NBUK], gb[NBUK];
    __shared__ int ssum[1024];
    __shared__ u32x2 st8[EPB];
    __shared__ float sv[EPB];
    int t = threadIdx.x;
    size_t base = (size_t)blockIdx.x * EPB;
    int total = (int)(((size_t)NNZ_ - base < (size_t)EPB) ? ((size_t)NNZ_ - base) : (size_t)EPB);
    if (t < NBUK) bukc[t] = 0;
    __syncthreads();
    size_t k = base + (size_t)t * 4;
    int bv[4]; uint32 tx[4], ty[4]; float vv[4];
    if (k + 4 <= NNZ_) {
        int4 rw = *(const int4*)(rows + k);
        int4 cw = *(const int4*)(cols + k);
        float4 vw = *(const float4*)(vals + k);
        int rr[4] = {rw.x, rw.y, rw.z, rw.w};
        int cc[4] = {cw.x, cw.y, cw.z, cw.w};
        vv[0] = vw.x; vv[1] = vw.y; vv[2] = vw.z; vv[3] = vw.w;
#pragma unroll
        for (int j = 0; j < 4; j++) {
            int rel = rr[j] / NNODES;
            int dst = rr[j] - rel * NNODES;
            bv[j] = dst >> 7;
            tx[j] = (uint32)dst | ((uint32)rel << 16);
            ty[j] = (uint32)cc[j] | ((uint32)rel << 16);
        }
    } else {
#pragma unroll
        for (int j = 0; j < 4; j++) {
            if (k + j < NNZ_) {
                int r = rows[k + j];
                int rel = r / NNODES;
                int dst = r - rel * NNODES;
                bv[j] = dst >> 7;
                tx[j] = (uint32)dst | ((uint32)rel << 16);
                ty[j] = (uint32)cols[k + j] | ((uint32)rel << 16);
                vv[j] = vals[k + j];
            } else bv[j] = -1;
        }
    }
#pragma unroll
    for (int j = 0; j < 4; j++)
        if (bv[j] >= 0) atomicAdd(&bukc[bv[j]], 1);
    __syncthreads();
    int v = (t < NBUK) ? bukc[t] : 0;
    ssum[t] = v;
    __syncthreads();
    for (int off = 1; off < 1024; off <<= 1) {
        int u = (t >= off) ? ssum[t - off] : 0;
        __syncthreads();
        ssum[t] += u;
        __syncthreads();
    }
    if (t < NBUK) { lb[t] = ssum[t] - v; gb[t] = atomicAdd(&buk_cur[t], v); }
    __syncthreads();
    if (t < NBUK) bukc[t] = 0;
    __syncthreads();
#pragma unroll
    for (int j = 0; j < 4; j++) {
        if (bv[j] >= 0) {
            int slot = lb[bv[j]] + atomicAdd(&bukc[bv[j]], 1);
            u32x2 w; w.x = tx[j]; w.y = ty[j];
            st8[slot] = w;
            sv[slot] = vv[j];
        }
    }
    __syncthreads();
    for (int s = t; s < total; s += 1024) {
        u32x2 w = st8[s];
        int bk = (int)((w.x & 0xFFFFu) >> 7);
        int pos = gb[bk] + (s - lb[bk]);
        tok8[pos] = w;
        sval_b[pos] = sv[s];
    }
}

// ---- fused count + rank + scatter per bucket. Region base via ONE global atomicAdd.
// ---- Segment ends stored explicitly (pdst_end) so unordered bucket bases are safe.
__global__ __launch_bounds__(256) void k_place3(const u32x2* __restrict__ tok8,
                                                const float* __restrict__ sval_b,
                                                const int* __restrict__ buk_base,
                                                int* __restrict__ alloc_cur,
                                                int* __restrict__ pdst_base,
                                                int* __restrict__ pdst_end,
                                                uint32* __restrict__ pe_sr,
                                                float* __restrict__ pe_val) {
    __shared__ int lcnt[128], lexc[128], lrank[128], ssc[128];
    __shared__ int bbase;
    int b = blockIdx.x, t = threadIdx.x;
    int lo = buk_base[b], hi = buk_base[b + 1];
    if (t < 128) { lcnt[t] = 0; lrank[t] = 0; }
    __syncthreads();
    for (int i = lo + t; i < hi; i += 256) atomicAdd(&lcnt[tok8[i].x & 127], 1);
    __syncthreads();
    int v = 0;
    int d = (b << 7) + t;
    if (t < 128) {
        v = (lcnt[t] + 15) & ~15;
        if (d < NNODES && v == 0) v = 16;
        if (d >= NNODES) v = 0;
        ssc[t] = v;
    }
    __syncthreads();
    for (int off = 1; off < 128; off <<= 1) {
        int u = (t >= off && t < 128) ? ssc[t - off] : 0;
        __syncthreads();
        if (t < 128) ssc[t] += u;
        __syncthreads();
    }
    if (t == 0) bbase = atomicAdd(alloc_cur, ssc[127]);
    __syncthreads();
    if (t < 128) {
        lexc[t] = ssc[t] - v;
        if (d < NNODES) {
            pdst_base[d] = bbase + lexc[t];
            pdst_end[d]  = bbase + ssc[t];   // within-bucket: == pdst_base[d+1]
        }
    }
    __syncthreads();
    for (int i = lo + t; i < hi; i += 256) {
        u32x2 w = tok8[i];
        float sv = sval_b[i];
        int dl = (int)(w.x & 127u);
        int pos = bbase + lexc[dl] + atomicAdd(&lrank[dl], 1);
        pe_sr[pos] = w.y;
        pe_val[pos] = sv;
    }
    if (t < 128 && d < NNODES) {
        int s0 = bbase + lexc[t] + lcnt[t];
        int s1 = bbase + lexc[t] + v;
        for (int i = s0; i < s1; i++) { pe_sr[i] = 0u; pe_val[i] = 0.f; }
    }
}

// ======== fused layer (r12 schedule; change: B-operand loaded DIRECTLY from global
// ======== Xb in fragment layout — lane m reads X[src_k][m] — eliminating the
// ======== gather/shfl/xst-transpose machinery, −32% LDS-pipe ops, bit-identical values)
// per-dst u = sum_e (val*comps[rel,:]) (x) X[src]   (32x32x16 MFMA, K=edge windows of 16)
// then h[dst] = u_flat(960) @ bases_flat(960 x FO)  (16x16x32 MFMA, 4-dst batches)
template <int FO, bool RELU, bool BF16OUT>
__global__ __launch_bounds__(256) void k_fused(const uint32* __restrict__ pe_sr,
                                               const float* __restrict__ pe_val,
                                               const int* __restrict__ pdst_base,
                                               const int* __restrict__ pdst_end,
                                               const u32x4* __restrict__ Xb,
                                               const u32x4* __restrict__ Wb,
                                               const float* __restrict__ comps,
                                               const float* __restrict__ bias,
                                               void* __restrict__ outp) {
    __shared__ ushort comps_lb[RREL * 32];            // bf16 comps: 3.3 KB
    __shared__ uint32 eds[4][64];
    __shared__ float edv[4][64];
    __shared__ __align__(16) ushort ubuf[4][4][968];  // [wave][slot][960 bf16]
    int t = threadIdx.x, lane = t & 63, wv = t >> 6;
    for (int i = t; i < RREL * 32; i += 256) {
        int r = i >> 5, b = i & 31;
        comps_lb[i] = (b < BB) ? bf16_1(comps[r * BB + b]) : (ushort)0;
    }
    __syncthreads();
    int m = lane & 31, hf = lane >> 5, k0 = hf * 8;
    int ln15 = lane & 15, quad = lane >> 4;
    int d0 = (blockIdx.x * 4 + wv) * 8;               // 8 dsts per wave; NNODES % 8 == 0
    if (d0 >= NNODES) return;                         // comps barrier already passed

    const ushort* Xm = (const ushort*)Xb + m;         // lane-fixed feature column

    // ---- pipeline prologue: meta for the wave's first chunk ----
    int base0 = pdst_base[d0];
    uint32 pvs = __builtin_nontemporal_load(&pe_sr[base0 + lane]);
    float  pvv = __builtin_nontemporal_load(&pe_val[base0 + lane]);

#pragma unroll 1
    for (int batch = 0; batch < 2; batch++) {
        int db = d0 + batch * 4;
        // ---- stage 1: accumulate u for 4 dsts into ubuf ----
#pragma unroll 1
        for (int s = 0; s < 4; s++) {
            int d = db + s;
            int lo = pdst_base[d], segEnd = pdst_end[d];
            f32x16 acc;
#pragma unroll
            for (int i = 0; i < 16; i++) acc[i] = 0.f;
#pragma unroll 1
            for (int c0 = lo; c0 < segEnd; c0 += 64) {
                eds[wv][lane] = pvs;                  // stage current meta (reg -> LDS)
                edv[wv][lane] = pvv;
                // issue next meta (regions contiguous & 16-granular within the wave's
                // 8-dst group: next chunk at min(c0+64, segEnd), even across dsts)
                int nxt = c0 + 64; if (nxt > segEnd) nxt = segEnd;
                uint32 npvs = __builtin_nontemporal_load(&pe_sr[nxt + lane]);
                float  npvv = __builtin_nontemporal_load(&pe_val[nxt + lane]);
                int nwin = (segEnd - c0) >> 4;
                if (nwin > 4) nwin = 4;
                // phase 1: per window, read meta from LDS, ISSUE 8 direct B-loads
                // (coalesced: lanes 0-31 read one 64B row), and pack the A-operand.
                // All loads are in flight before the first MFMA waits.
                u32x4 av[4];
                uint32 bx[4][8];
#pragma unroll
                for (int wi = 0; wi < 4; wi++) {
                    if (wi < nwin) {
                        uint32 sr[8]; float vv[8];
#pragma unroll
                        for (int j = 0; j < 8; j++) {
                            sr[j] = eds[wv][wi * 16 + k0 + j];
                            vv[j] = edv[wv][wi * 16 + k0 + j];
                        }
#pragma unroll
                        for (int j = 0; j < 8; j++)
                            bx[wi][j] = (uint32)Xm[(size_t)(sr[j] & 0xFFFFu) * 32];
                        float cc[8];
#pragma unroll
                        for (int j = 0; j < 8; j++) {
                            uint32 cu = (uint32)comps_lb[((sr[j] >> 16) << 5) | m] << 16;
                            cc[j] = vv[j] * __builtin_bit_cast(float, cu);
                        }
                        av[wi] = u32x4{ pack_bf16x2(cc[0], cc[1]), pack_bf16x2(cc[2], cc[3]),
                                        pack_bf16x2(cc[4], cc[5]), pack_bf16x2(cc[6], cc[7]) };
                    }
                }
                // phase 2: pack B and MFMA per window
#pragma unroll
                for (int wi = 0; wi < 4; wi++) {
                    if (wi < nwin) {
                        u32x4 bvq = { bx[wi][0] | (bx[wi][1] << 16), bx[wi][2] | (bx[wi][3] << 16),
                                      bx[wi][4] | (bx[wi][5] << 16), bx[wi][6] | (bx[wi][7] << 16) };
                        acc = __builtin_amdgcn_mfma_f32_32x32x16_bf16(
                            __builtin_bit_cast(bf16x8, av[wi]), __builtin_bit_cast(bf16x8, bvq),
                            acc, 0, 0, 0);
                    }
                }
                pvs = npvs; pvv = npvv;
            }
            // flush u (C-layout: col f = m, row b per reg) -> ubuf[wv][s] as bf16 rows k=b*32+f
#pragma unroll
            for (int r = 0; r < 16; r++) {
                int b = (r & 3) + 8 * (r >> 2) + 4 * hf;
                float vme = acc[r];
                float vot = __shfl_xor(vme, 1, 64);
                if (b < BB && !(m & 1)) {
                    *(uint32*)&ubuf[wv][s][b * 32 + m] = pack_bf16x2(vme, vot);
                }
            }
        }
        // ---- stage 2: h[db..db+3] = u @ bases_flat ----
        const int NT = FO / 16;
        f32x4 a2[NT];
#pragma unroll
        for (int tt = 0; tt < NT; tt++)
#pragma unroll
            for (int i = 0; i < 4; i++) a2[tt][i] = 0.f;
#pragma unroll 6
        for (int ks = 0; ks < 30; ks++) {
            bf16x8 af = *(const bf16x8*)&ubuf[wv][ln15 & 3][ks * 32 + quad * 8];
#pragma unroll
            for (int tt = 0; tt < NT; tt++) {
                bf16x8 bf2 = __builtin_bit_cast(bf16x8, Wb[(ks * 4 + quad) * FO + ln15 + 16 * tt]);
                a2[tt] = __builtin_amdgcn_mfma_f32_16x16x32_bf16(af, bf2, a2[tt], 0, 0, 0);
            }
        }
        if (quad == 0) {
#pragma unroll
            for (int r = 0; r < 4; r++) {
                int dst = db + r;
                if (dst < NNODES) {
                    if (BF16OUT) {
                        ushort* hp = (ushort*)outp;
#pragma unroll
                        for (int tt = 0; tt < NT; tt++) {
                            float o = a2[tt][r] + bias[ln15 + 16 * tt];
                            if (RELU) o = fmaxf(o, 0.f);
                            hp[(size_t)dst * FO + ln15 + 16 * tt] = bf16_1(o);
                        }
                    } else {
                        float o = a2[0][r] + bias[ln15];
                        if (RELU) o = fmaxf(o, 0.f);
                        ((float*)outp)[(size_t)dst * FO + ln15] = o;
                    }
                }
            }
        }
    }
}

extern "C" void kernel_launch(void* const* d_in, const int* in_sizes, int n_in,
                              void* d_out, int out_size, void* d_ws, size_t ws_size,
                              hipStream_t stream) {
    const float* features = (const float*)d_in[0];
    const float* vals     = (const float*)d_in[1];
    const float* comps1   = (const float*)d_in[2];
    const float* bases1   = (const float*)d_in[3];
    const float* bias1    = (const float*)d_in[4];
    const float* comps2   = (const float*)d_in[5];
    const float* bases2   = (const float*)d_in[6];
    const float* bias2    = (const float*)d_in[7];
    const int*   rows     = (const int*)d_in[8];
    const int*   cols     = (const int*)d_in[9];
    float* out = (float*)d_out;

    // ---- workspace layout (4-byte units); ~54 MB total ----
    float* ws = (float*)d_ws;
    size_t o = 0;
    ushort* Wb1 = (ushort*)(ws + o); o += 960 * 32 / 2;              // 15360 u32
    ushort* Wb2 = (ushort*)(ws + o); o += 960 * 16 / 2;              // 7680
    uint32* Xb  = (uint32*)(ws + o); o += (size_t)NNODES * 16;       // 3.2 MB (64 B bf16 rows)
    uint32* h1b = (uint32*)(ws + o); o += (size_t)NNODES * 16;       // 3.2 MB
    uint32* pe_sr  = (uint32*)(ws + o); o += PCAP_MAX;               // src|rel<<16, dst-sorted padded
    float*  pe_val = (float*)(ws + o);  o += PCAP_MAX;
    int* pdst_base = (int*)(ws + o); o += NNODES + 8;
    int* pdst_end  = (int*)(ws + o); o += NNODES + 8;
    // contiguous zero region: buk_cnt .. alloc_cur
    int* buk_cnt   = (int*)(ws + o); o += NBUK;
    int* alloc_cur = (int*)(ws + o); o += 1;
    int* buk_base  = (int*)(ws + o); o += NBUK + 1;
    int* buk_cur   = (int*)(ws + o); o += NBUK;
    o = (o + 1) & ~(size_t)1;
    u32x2* tok8 = (u32x2*)(ws + o); o += 2 * (size_t)NNZ_;           // 16 MB
    float* sval_b = (float*)(ws + o); o += (size_t)NNZ_;             // 8 MB

    const int NB = (NNZ_ + EPB - 1) / EPB;    // 489

    hipMemsetAsync(buk_cnt, 0, (NBUK + 1) * sizeof(int), stream);    // buk_cnt + alloc_cur

    k_weights2<<<(960 * 32 + 255) / 256, 256, 0, stream>>>(bases1, bases2, Wb1, Wb2);
    k_tobf16<<<(NNODES * FIN / 2 + 255) / 256, 256, 0, stream>>>((const float2*)features, Xb,
                                                                 NNODES * FIN / 2);
    k_bukhist<<<NB, 1024, 0, stream>>>(rows, buk_cnt);
    k_scan1<<<1, 64, 0, stream>>>(buk_cnt, buk_base, buk_cur);
    k_bucket2<<<NB, 1024, 0, stream>>>(rows, cols, vals, buk_cur, tok8, sval_b);
    k_place3<<<NBUK, 256, 0, stream>>>(tok8, sval_b, buk_base, alloc_cur, pdst_base, pdst_end,
                                       pe_sr, pe_val);

    // 50000 dsts / 8 per wave / 4 waves per block = 1563 blocks (tail waves idle)
    k_fused<EDIM, true, true><<<(NNODES + 31) / 32, 256, 0, stream>>>(
        pe_sr, pe_val, pdst_base, pdst_end, (const u32x4*)Xb, (const u32x4*)Wb1, comps1, bias1, h1b);
    k_fused<CDIM, false, false><<<(NNODES + 31) / 32, 256, 0, stream>>>(
        pe_sr, pe_val, pdst_base, pdst_end, (const u32x4*)h1b, (const u32x4*)Wb2, comps2, bias2, out);
}